// Round 8
// baseline (1171.207 us; speedup 1.0000x reference)
//
#include <hip/hip_runtime.h>
#include <stdint.h>

#define BB 8
#define NN 4096
#define CC 64
#define MM 1024
#define EE (BB*MM)   // 8192 centroids
#define KK 64        // max neighbors
#define F3 256       // output channels
#define SM 104       // msg LDS stride (elements), 16B-aligned rows (208 B)
#define SH 136       // h LDS stride (elements), 16B-aligned rows (272 B)
#define CAP 768      // candidate buffer

typedef __bf16 bf16x8 __attribute__((ext_vector_type(8)));
typedef float floatx4 __attribute__((ext_vector_type(4)));

// ---- wave64 reductions via DPP (round-3-verified) ----
#define DPP_MAXSTEP(ctrl, rmask) { \
    unsigned o = (unsigned)__builtin_amdgcn_update_dpp(0, (int)v, ctrl, rmask, 0xf, false); \
    v = v > o ? v : o; }
__device__ __forceinline__ unsigned wave_umax_u32(unsigned v) {
  DPP_MAXSTEP(0x111, 0xf)
  DPP_MAXSTEP(0x112, 0xf)
  DPP_MAXSTEP(0x114, 0xf)
  DPP_MAXSTEP(0x118, 0xf)
  DPP_MAXSTEP(0x142, 0xa)
  DPP_MAXSTEP(0x143, 0xc)
  return (unsigned)__builtin_amdgcn_readlane((int)v, 63);
}
#define DPP_MINSTEP(ctrl, rmask) { \
    unsigned o = (unsigned)__builtin_amdgcn_update_dpp((int)0xffffffffu, (int)v, ctrl, rmask, 0xf, false); \
    v = v < o ? v : o; }
__device__ __forceinline__ unsigned wave_umin_u32(unsigned v) {
  DPP_MINSTEP(0x111, 0xf)
  DPP_MINSTEP(0x112, 0xf)
  DPP_MINSTEP(0x114, 0xf)
  DPP_MINSTEP(0x118, 0xf)
  DPP_MINSTEP(0x142, 0xa)
  DPP_MINSTEP(0x143, 0xc)
  return (unsigned)__builtin_amdgcn_readlane((int)v, 63);
}

// ---- FPS: TWO graphs per block (blocks 0..3), ILP-paired -------------------
// Per-graph numerics byte-identical to round-3-verified loop; graph B's inner
// VALU fills graph A's DPP/LDS dependency stalls (1 wave/SIMD otherwise idle),
// one barrier serves both chains. LDS 128KB -> 1 block/CU; only 4 CUs active
// so chip stays at boost clock (r5 lesson: co-running work collapses clocks).
// wprep blocks 4..243, posp blocks 244..371.
__global__ __launch_bounds__(256, 1) void fps_prep_kernel(
    const float* __restrict__ pos,
    const float* __restrict__ W1, const float* __restrict__ W2, const float* __restrict__ W3,
    int* __restrict__ fpsIdx, float* __restrict__ ctr,
    __bf16* __restrict__ W1t, __bf16* __restrict__ W2t, __bf16* __restrict__ W3t,
    float4* __restrict__ pos4) {
  __shared__ float4 sP4[2][NN];                    // 128 KB
  __shared__ unsigned long long sRed[2][2][4];     // [graph][dbuf][wave]
  const int blk = blockIdx.x;
  const int t = threadIdx.x;

  if (blk >= 4) {
    if (blk < 244) {                               // wprep: 61440 elements, 240 blocks
      const int i0 = (blk - 4) * 256 + t;
      if (i0 < 128 * 96) {
        const int n = i0 / 96, k = i0 % 96;
        W1t[i0] = (k < 67) ? (__bf16)W1[k * 128 + n] : (__bf16)0.0f;
      } else if (i0 < 128 * 96 + 128 * 128) {
        const int i = i0 - 128 * 96;
        const int n = i / 128, k = i % 128;
        W2t[i] = (__bf16)W2[k * 128 + n];
      } else {
        const int i = i0 - (128 * 96 + 128 * 128);
        const int n = i / 128, k = i % 128;
        W3t[i] = (__bf16)W3[k * 256 + n];
      }
    } else {                                       // posp: 32768 points, 128 blocks
      const int i = (blk - 244) * 256 + t;
      pos4[i] = make_float4(pos[(long)i * 3 + 0], pos[(long)i * 3 + 1],
                            pos[(long)i * 3 + 2], 0.0f);
    }
    return;
  }

  const int gA = blk * 2, gB = gA + 1;
  const int lane = t & 63, wv = t >> 6;            // 4 waves
  float pxA[16], pyA[16], pzA[16], mindA[16];
  float pxB[16], pyB[16], pzB[16], mindB[16];
#pragma unroll
  for (int j = 0; j < 16; ++j) {
    const int p = t + (j << 8);
    {
      const long base = ((long)gA * NN + p) * 3;
      pxA[j] = pos[base + 0]; pyA[j] = pos[base + 1]; pzA[j] = pos[base + 2];
      mindA[j] = 1e10f;
      sP4[0][p] = make_float4(pxA[j], pyA[j], pzA[j], 0.0f);
    }
    {
      const long base = ((long)gB * NN + p) * 3;
      pxB[j] = pos[base + 0]; pyB[j] = pos[base + 1]; pzB[j] = pos[base + 2];
      mindB[j] = 1e10f;
      sP4[1][p] = make_float4(pxB[j], pyB[j], pzB[j], 0.0f);
    }
  }
  __syncthreads();
  float wxA, wyA, wzA, wxB, wyB, wzB;
  { const float4 w0 = sP4[0][0]; wxA = w0.x; wyA = w0.y; wzA = w0.z; }
  { const float4 w0 = sP4[1][0]; wxB = w0.x; wyB = w0.y; wzB = w0.z; }
  int winA0 = 0, winA1 = 0, winA2 = 0, winA3 = 0;
  int winB0 = 0, winB1 = 0, winB2 = 0, winB3 = 0;
  for (int s = 1; s < MM; ++s) {
    // --- inner A (exact r3 numerics) ---
    unsigned bbA = 0u, bidxA = (unsigned)t;
#pragma unroll
    for (int j = 0; j < 16; ++j) {
      const float dx = __fsub_rn(pxA[j], wxA);
      const float dy = __fsub_rn(pyA[j], wyA);
      const float dz = __fsub_rn(pzA[j], wzA);
      const float d2 = __fadd_rn(__fadd_rn(__fmul_rn(dx, dx), __fmul_rn(dy, dy)), __fmul_rn(dz, dz));
      mindA[j] = fminf(mindA[j], d2);
      const unsigned mb = __float_as_uint(mindA[j]);
      if (mb > bbA) { bbA = mb; bidxA = (unsigned)(t + (j << 8)); }
    }
    // --- inner B (independent chain; fills A's stalls) ---
    unsigned bbB = 0u, bidxB = (unsigned)t;
#pragma unroll
    for (int j = 0; j < 16; ++j) {
      const float dx = __fsub_rn(pxB[j], wxB);
      const float dy = __fsub_rn(pyB[j], wyB);
      const float dz = __fsub_rn(pzB[j], wzB);
      const float d2 = __fadd_rn(__fadd_rn(__fmul_rn(dx, dx), __fmul_rn(dy, dy)), __fmul_rn(dz, dz));
      mindB[j] = fminf(mindB[j], d2);
      const unsigned mb = __float_as_uint(mindB[j]);
      if (mb > bbB) { bbB = mb; bidxB = (unsigned)(t + (j << 8)); }
    }
    // --- wave reduces: A and B chains independent -> latencies overlap ---
    const unsigned maxvA = wave_umax_u32(bbA);
    const unsigned maxvB = wave_umax_u32(bbB);
    const unsigned widxA = wave_umin_u32((bbA == maxvA) ? bidxA : 0xffffffffu);
    const unsigned widxB = wave_umin_u32((bbB == maxvB) ? bidxB : 0xffffffffu);
    if (lane == 0) {
      sRed[0][s & 1][wv] = ((unsigned long long)maxvA << 32) | (unsigned long long)(~widxA);
      sRed[1][s & 1][wv] = ((unsigned long long)maxvB << 32) | (unsigned long long)(~widxB);
    }
    __syncthreads();                               // ONE barrier for both graphs
    // --- cross-wave scans + winner broadcasts (independent -> overlap) ---
    unsigned long long mA = sRed[0][s & 1][0];
    unsigned long long mB = sRed[1][s & 1][0];
#pragma unroll
    for (int w = 1; w < 4; ++w) {
      const unsigned long long oA = sRed[0][s & 1][w];
      const unsigned long long oB = sRed[1][s & 1][w];
      mA = oA > mA ? oA : mA;
      mB = oB > mB ? oB : mB;
    }
    const int wiA = (int)(~(unsigned)mA);
    const int wiB = (int)(~(unsigned)mB);
    const float4 wpA = sP4[0][wiA];
    const float4 wpB = sP4[1][wiB];
    wxA = wpA.x; wyA = wpA.y; wzA = wpA.z;
    wxB = wpB.x; wyB = wpB.y; wzB = wpB.z;
    winA0 = (s == t)       ? wiA : winA0;
    winA1 = (s == t + 256) ? wiA : winA1;
    winA2 = (s == t + 512) ? wiA : winA2;
    winA3 = (s == t + 768) ? wiA : winA3;
    winB0 = (s == t)       ? wiB : winB0;
    winB1 = (s == t + 256) ? wiB : winB1;
    winB2 = (s == t + 512) ? wiB : winB2;
    winB3 = (s == t + 768) ? wiB : winB3;
  }
  {
    const long eA = (long)gA * MM + t;
    const float4 a0 = sP4[0][winA0];
    fpsIdx[eA] = winA0;
    ctr[eA * 3 + 0] = a0.x; ctr[eA * 3 + 1] = a0.y; ctr[eA * 3 + 2] = a0.z;
    const float4 a1 = sP4[0][winA1];
    fpsIdx[eA + 256] = winA1;
    ctr[(eA + 256) * 3 + 0] = a1.x; ctr[(eA + 256) * 3 + 1] = a1.y; ctr[(eA + 256) * 3 + 2] = a1.z;
    const float4 a2 = sP4[0][winA2];
    fpsIdx[eA + 512] = winA2;
    ctr[(eA + 512) * 3 + 0] = a2.x; ctr[(eA + 512) * 3 + 1] = a2.y; ctr[(eA + 512) * 3 + 2] = a2.z;
    const float4 a3 = sP4[0][winA3];
    fpsIdx[eA + 768] = winA3;
    ctr[(eA + 768) * 3 + 0] = a3.x; ctr[(eA + 768) * 3 + 1] = a3.y; ctr[(eA + 768) * 3 + 2] = a3.z;
    const long eB = (long)gB * MM + t;
    const float4 b0 = sP4[1][winB0];
    fpsIdx[eB] = winB0;
    ctr[eB * 3 + 0] = b0.x; ctr[eB * 3 + 1] = b0.y; ctr[eB * 3 + 2] = b0.z;
    const float4 b1v = sP4[1][winB1];
    fpsIdx[eB + 256] = winB1;
    ctr[(eB + 256) * 3 + 0] = b1v.x; ctr[(eB + 256) * 3 + 1] = b1v.y; ctr[(eB + 256) * 3 + 2] = b1v.z;
    const float4 b2v = sP4[1][winB2];
    fpsIdx[eB + 512] = winB2;
    ctr[(eB + 512) * 3 + 0] = b2v.x; ctr[(eB + 512) * 3 + 1] = b2v.y; ctr[(eB + 512) * 3 + 2] = b2v.z;
    const float4 b3v = sP4[1][winB3];
    fpsIdx[eB + 768] = winB3;
    ctr[(eB + 768) * 3 + 0] = b3v.x; ctr[(eB + 768) * 3 + 1] = b3v.y; ctr[(eB + 768) * 3 + 2] = b3v.z;
  }
}

// ---- Fused radius-search + rank-top-K + gather + 3-layer MLP (MFMA) + masked max ----
// EXACT round-3-verified version (512 thr = 8 waves, 250us measured).
// r7 measured: item latency scales with per-wave serial work -> smaller blocks lose.
__global__ __launch_bounds__(512) void mlp_kernel(const float* __restrict__ x,
    const float4* __restrict__ pos4, const float* __restrict__ ctr,
    const int* __restrict__ fpsIdx,
    const __bf16* __restrict__ W1t, const __bf16* __restrict__ W2t,
    const __bf16* __restrict__ W3t,
    const float* __restrict__ b1, const float* __restrict__ b2,
    const float* __restrict__ b3,
    float* __restrict__ outX, float* __restrict__ outP,
    float* __restrict__ outB, float* __restrict__ outS) {
  __shared__ __align__(16) __bf16 sMsg[64 * SM];   // 13312 B; overlays sDI (6144 B)
  __shared__ __align__(16) __bf16 sH[64 * SH];     // 17408 B
  __shared__ int sSel[KK];
  __shared__ int sCnt;
  unsigned long long* sDI = (unsigned long long*)sMsg;  // [CAP] packed (d2bits<<32 | idx)

  const int e = blockIdx.x;
  const int t = threadIdx.x;
  const int b = e >> 10;
  const int lane = t & 63, wv = t >> 6;

  if (t == 0) sCnt = 0;
  const float cx = ctr[(long)e * 3 + 0];
  const float cy = ctr[(long)e * 3 + 1];
  const float cz = ctr[(long)e * 3 + 2];
  if (t < 3) outP[(long)e * 3 + t] = ctr[(long)e * 3 + t];
  if (t == 3) { outB[e] = (float)b; outS[e] = (float)(b * NN + fpsIdx[e]); }
  const float R2 = (float)(0.2 * 0.2);
  __syncthreads();

  // Phase A: scan 4096 points (float4 loads); ballot-compact candidates to LDS.
#pragma unroll
  for (int q = 0; q < NN / 512; ++q) {
    const int p = t + q * 512;
    const float4 P = pos4[b * NN + p];
    const float dx = __fsub_rn(cx, P.x);
    const float dy = __fsub_rn(cy, P.y);
    const float dz = __fsub_rn(cz, P.z);
    const float d2 = __fadd_rn(__fadd_rn(__fmul_rn(dx, dx), __fmul_rn(dy, dy)), __fmul_rn(dz, dz));
    const bool v = d2 < R2;
    const unsigned long long mask = __ballot(v);
    int wbase = 0;
    if (lane == 0 && mask) wbase = atomicAdd(&sCnt, (int)__popcll(mask));
    wbase = __shfl(wbase, 0);
    if (v) {
      const int off = wbase + (int)__popcll(mask & ((1ull << lane) - 1ull));
      if (off < CAP)
        sDI[off] = ((unsigned long long)__float_as_uint(d2) << 32) | (unsigned)p;
    }
  }
  __syncthreads();
  int cnt = sCnt; cnt = cnt > CAP ? CAP : cnt;
  const int nsel = cnt < KK ? cnt : KK;

  // Phase B: parallel rank selection. rank(i) = #{j : key_j < key_i}; keep rank<K.
  for (int i = t; i < cnt; i += 512) {
    const unsigned long long my = sDI[i];
    int rank = 0;
#pragma unroll 8
    for (int j = 0; j < cnt; ++j) rank += (sDI[j] < my) ? 1 : 0;
    if (rank < KK) sSel[rank] = (int)(unsigned)(my & 0xffffffffu);
  }
  __syncthreads();   // sDI dead from here; sMsg may be written
  cnt = nsel;

  // Phase C: stage msg tile [64 x (64 feat | 3 dpos | zero-pad)] into LDS as bf16.
  {
    const int r = t >> 3, p = t & 7;
    float4 a = make_float4(0.f, 0.f, 0.f, 0.f), c4 = a;
    if (r < cnt) {
      const float* xr = x + (long)(b * NN + sSel[r]) * CC + p * 8;
      a  = *(const float4*)xr;
      c4 = *(const float4*)(xr + 4);
    }
    __bf16 o[8] = {(__bf16)a.x, (__bf16)a.y, (__bf16)a.z, (__bf16)a.w,
                   (__bf16)c4.x, (__bf16)c4.y, (__bf16)c4.z, (__bf16)c4.w};
    *(uint4*)&sMsg[r * SM + p * 8] = *(uint4*)o;
  }
  if (t < 64) {
    const int r = t;
    __bf16 d0 = (__bf16)0.0f, d1 = (__bf16)0.0f, d2v = (__bf16)0.0f;
    if (r < cnt) {
      const float4 P = pos4[b * NN + sSel[r]];
      d0  = (__bf16)__fsub_rn(P.x, cx);
      d1  = (__bf16)__fsub_rn(P.y, cy);
      d2v = (__bf16)__fsub_rn(P.z, cz);
    }
    sMsg[r * SM + 64] = d0;
    sMsg[r * SM + 65] = d1;
    sMsg[r * SM + 66] = d2v;
    for (int c = 67; c < SM; ++c) sMsg[r * SM + c] = (__bf16)0.0f;
  }
  __syncthreads();

  const int l15 = lane & 15, quad = lane >> 4;
  // ---- layer 1: [64 x 96] @ [96 x 128] -> sH; wave wv owns n-tile wv ----
  {
    floatx4 acc[4] = {};
    const __bf16* wrow = W1t + (wv * 16 + l15) * 96;
#pragma unroll
    for (int ks = 0; ks < 3; ++ks) {
      const bf16x8 bfrag = *(const bf16x8*)(wrow + ks * 32 + quad * 8);
#pragma unroll
      for (int mt = 0; mt < 4; ++mt) {
        const bf16x8 afrag = *(const bf16x8*)&sMsg[(mt * 16 + l15) * SM + ks * 32 + quad * 8];
        acc[mt] = __builtin_amdgcn_mfma_f32_16x16x32_bf16(afrag, bfrag, acc[mt], 0, 0, 0);
      }
    }
    const int col = wv * 16 + l15;
    const float bias = b1[col];
#pragma unroll
    for (int mt = 0; mt < 4; ++mt)
#pragma unroll
      for (int rg = 0; rg < 4; ++rg) {
        const int row = mt * 16 + quad * 4 + rg;
        float v = acc[mt][rg] + bias;
        v = v > 0.0f ? v : 0.0f;
        sH[row * SH + col] = (__bf16)v;
      }
  }
  __syncthreads();
  // ---- layer 2: [64 x 128] @ [128 x 128], IN PLACE on sH ----
  {
    floatx4 acc[4] = {};
    const __bf16* wrow = W2t + (wv * 16 + l15) * 128;
#pragma unroll
    for (int ks = 0; ks < 4; ++ks) {
      const bf16x8 bfrag = *(const bf16x8*)(wrow + ks * 32 + quad * 8);
#pragma unroll
      for (int mt = 0; mt < 4; ++mt) {
        const bf16x8 afrag = *(const bf16x8*)&sH[(mt * 16 + l15) * SH + ks * 32 + quad * 8];
        acc[mt] = __builtin_amdgcn_mfma_f32_16x16x32_bf16(afrag, bfrag, acc[mt], 0, 0, 0);
      }
    }
    __syncthreads();
    const int col = wv * 16 + l15;
    const float bias = b2[col];
#pragma unroll
    for (int mt = 0; mt < 4; ++mt)
#pragma unroll
      for (int rg = 0; rg < 4; ++rg) {
        const int row = mt * 16 + quad * 4 + rg;
        float v = acc[mt][rg] + bias;
        v = v > 0.0f ? v : 0.0f;
        sH[row * SH + col] = (__bf16)v;
      }
  }
  __syncthreads();
  // ---- layer 3: [64 x 128] @ [128 x 256]; wave owns 2 n-tiles; fused masked max ----
  {
    floatx4 acc[2][4] = {};
#pragma unroll
    for (int ks = 0; ks < 4; ++ks) {
      bf16x8 afrag[4];
#pragma unroll
      for (int mt = 0; mt < 4; ++mt)
        afrag[mt] = *(const bf16x8*)&sH[(mt * 16 + l15) * SH + ks * 32 + quad * 8];
#pragma unroll
      for (int i = 0; i < 2; ++i) {
        const bf16x8 bfrag = *(const bf16x8*)(W3t + ((wv * 2 + i) * 16 + l15) * 128 + ks * 32 + quad * 8);
#pragma unroll
        for (int mt = 0; mt < 4; ++mt)
          acc[i][mt] = __builtin_amdgcn_mfma_f32_16x16x32_bf16(afrag[mt], bfrag, acc[i][mt], 0, 0, 0);
      }
    }
#pragma unroll
    for (int i = 0; i < 2; ++i) {
      const int col = (wv * 2 + i) * 16 + l15;
      const float bias = b3[col];
      float mx = 0.0f;  // centroid itself always in-radius => cnt>=1; ReLU >= 0
#pragma unroll
      for (int mt = 0; mt < 4; ++mt)
#pragma unroll
        for (int rg = 0; rg < 4; ++rg) {
          const int row = mt * 16 + quad * 4 + rg;
          float v = acc[i][mt][rg] + bias;
          v = v > 0.0f ? v : 0.0f;
          if (row < cnt) mx = fmaxf(mx, v);
        }
      mx = fmaxf(mx, __shfl_xor(mx, 16));
      mx = fmaxf(mx, __shfl_xor(mx, 32));
      if (quad == 0) outX[(long)e * F3 + col] = mx;
    }
  }
}

extern "C" void kernel_launch(void* const* d_in, const int* in_sizes, int n_in,
                              void* d_out, int out_size, void* d_ws, size_t ws_size,
                              hipStream_t stream) {
  const float* x   = (const float*)d_in[0];
  const float* pos = (const float*)d_in[1];
  const float* W1  = (const float*)d_in[4];
  const float* b1  = (const float*)d_in[5];
  const float* W2  = (const float*)d_in[6];
  const float* b2  = (const float*)d_in[7];
  const float* W3  = (const float*)d_in[8];
  const float* b3  = (const float*)d_in[9];

  // Workspace layout (~778 KB)
  char* ws = (char*)d_ws;
  int*    fpsIdx = (int*)(ws);                 // 32768
  float*  ctr    = (float*)(ws + 32768);       // 98304   (ends 131072)
  __bf16* W1t    = (__bf16*)(ws + 131072);     // 24576   (ends 155648)
  __bf16* W2t    = (__bf16*)(ws + 155648);     // 32768   (ends 188416)
  __bf16* W3t    = (__bf16*)(ws + 188416);     // 65536   (ends 253952)
  float4* pos4   = (float4*)(ws + 253952);     // 524288  (ends 778240)

  float* outX = (float*)d_out;                 // [8192,256]
  float* outP = outX + (long)EE * F3;          // [8192,3]
  float* outB = outP + (long)EE * 3;           // [8192]
  float* outS = outB + EE;                     // [8192]

  // blocks: 4 paired-FPS + 240 wprep + 128 posp (256 threads each)
  fps_prep_kernel<<<372, 256, 0, stream>>>(pos, W1, W2, W3,
                                           fpsIdx, ctr, W1t, W2t, W3t, pos4);
  mlp_kernel<<<EE, 512, 0, stream>>>(x, pos4, ctr, fpsIdx, W1t, W2t, W3t,
                                     b1, b2, b3, outX, outP, outB, outS);
}

// Round 9
// 868.891 us; speedup vs baseline: 1.3479x; 1.3479x over previous
//
#include <hip/hip_runtime.h>
#include <stdint.h>

#define BB 8
#define NN 4096
#define CC 64
#define MM 1024
#define EE (BB*MM)   // 8192 centroids
#define KK 64        // max neighbors
#define F3 256       // output channels
#define SM 104       // msg LDS stride (elements), 16B-aligned rows (208 B)
#define SH 136       // h LDS stride (elements), 16B-aligned rows (272 B)
#define CAP 768      // candidate buffer

typedef __bf16 bf16x8 __attribute__((ext_vector_type(8)));
typedef float floatx4 __attribute__((ext_vector_type(4)));

// ---- wave64 reductions via DPP (round-3-verified) ----
#define DPP_MAXSTEP(ctrl, rmask) { \
    unsigned o = (unsigned)__builtin_amdgcn_update_dpp(0, (int)v, ctrl, rmask, 0xf, false); \
    v = v > o ? v : o; }
__device__ __forceinline__ unsigned wave_umax_u32(unsigned v) {
  DPP_MAXSTEP(0x111, 0xf)
  DPP_MAXSTEP(0x112, 0xf)
  DPP_MAXSTEP(0x114, 0xf)
  DPP_MAXSTEP(0x118, 0xf)
  DPP_MAXSTEP(0x142, 0xa)
  DPP_MAXSTEP(0x143, 0xc)
  return (unsigned)__builtin_amdgcn_readlane((int)v, 63);
}
#define DPP_MINSTEP(ctrl, rmask) { \
    unsigned o = (unsigned)__builtin_amdgcn_update_dpp((int)0xffffffffu, (int)v, ctrl, rmask, 0xf, false); \
    v = v < o ? v : o; }
__device__ __forceinline__ unsigned wave_umin_u32(unsigned v) {
  DPP_MINSTEP(0x111, 0xf)
  DPP_MINSTEP(0x112, 0xf)
  DPP_MINSTEP(0x114, 0xf)
  DPP_MINSTEP(0x118, 0xf)
  DPP_MINSTEP(0x142, 0xa)
  DPP_MINSTEP(0x143, 0xc)
  return (unsigned)__builtin_amdgcn_readlane((int)v, 63);
}

// ---- FPS (blocks 0..7, 4 waves) + W transpose (8..247) + pos->float4 (248..375) ----
// BYTE-IDENTICAL to round-3 verified version (578 us measured, 3x). FPS structure
// space is measured-exhausted (8wv:612, 4wv:578, pk:733, paired:926, overlap:~855).
// Do not touch.
__global__ __launch_bounds__(256) void fps_prep_kernel(
    const float* __restrict__ pos,
    const float* __restrict__ W1, const float* __restrict__ W2, const float* __restrict__ W3,
    int* __restrict__ fpsIdx, float* __restrict__ ctr,
    __bf16* __restrict__ W1t, __bf16* __restrict__ W2t, __bf16* __restrict__ W3t,
    float4* __restrict__ pos4) {
  __shared__ float4 sP4[NN];                       // 64 KB
  __shared__ unsigned long long sRed[2][4];
  const int blk = blockIdx.x;
  const int t = threadIdx.x;

  if (blk >= BB) {
    if (blk < 248) {                               // wprep: 61440 elements, 240 blocks
      const int i0 = (blk - 8) * 256 + t;
      if (i0 < 128 * 96) {
        const int n = i0 / 96, k = i0 % 96;
        W1t[i0] = (k < 67) ? (__bf16)W1[k * 128 + n] : (__bf16)0.0f;
      } else if (i0 < 128 * 96 + 128 * 128) {
        const int i = i0 - 128 * 96;
        const int n = i / 128, k = i % 128;
        W2t[i] = (__bf16)W2[k * 128 + n];
      } else {
        const int i = i0 - (128 * 96 + 128 * 128);
        const int n = i / 128, k = i % 128;
        W3t[i] = (__bf16)W3[k * 256 + n];
      }
    } else {                                       // posp: 32768 points, 128 blocks
      const int i = (blk - 248) * 256 + t;
      pos4[i] = make_float4(pos[(long)i * 3 + 0], pos[(long)i * 3 + 1],
                            pos[(long)i * 3 + 2], 0.0f);
    }
    return;
  }

  const int g = blk;
  const int lane = t & 63, wv = t >> 6;            // 4 waves
  float px[16], py[16], pz[16], mind[16];
#pragma unroll
  for (int j = 0; j < 16; ++j) {
    const int p = t + (j << 8);
    const long base = ((long)g * NN + p) * 3;
    px[j] = pos[base + 0];
    py[j] = pos[base + 1];
    pz[j] = pos[base + 2];
    mind[j] = 1e10f;
    sP4[p] = make_float4(px[j], py[j], pz[j], 0.0f);
  }
  __syncthreads();
  float wx, wy, wz;
  { const float4 w0 = sP4[0]; wx = w0.x; wy = w0.y; wz = w0.z; }
  int win0 = 0, win1 = 0, win2 = 0, win3 = 0;      // static regs, no dynamic idx
  for (int s = 1; s < MM; ++s) {
    unsigned bb = 0u, bidx = (unsigned)t;
#pragma unroll
    for (int j = 0; j < 16; ++j) {
      const float dx = __fsub_rn(px[j], wx);
      const float dy = __fsub_rn(py[j], wy);
      const float dz = __fsub_rn(pz[j], wz);
      const float d2 = __fadd_rn(__fadd_rn(__fmul_rn(dx, dx), __fmul_rn(dy, dy)), __fmul_rn(dz, dz));
      mind[j] = fminf(mind[j], d2);
      const unsigned mb = __float_as_uint(mind[j]);   // positive floats: bit order == value order
      if (mb > bb) { bb = mb; bidx = (unsigned)(t + (j << 8)); }  // strict >: smallest j on tie
    }
    const unsigned maxv = wave_umax_u32(bb);
    const unsigned cand = (bb == maxv) ? bidx : 0xffffffffu;
    const unsigned widx_w = wave_umin_u32(cand);
    if (lane == 0)
      sRed[s & 1][wv] = ((unsigned long long)maxv << 32) | (unsigned long long)(~widx_w);
    __syncthreads();
    unsigned long long m = sRed[s & 1][0];
#pragma unroll
    for (int w = 1; w < 4; ++w) {
      const unsigned long long o = sRed[s & 1][w];
      m = o > m ? o : m;
    }
    const int widx = (int)(~(unsigned)m);
    const float4 wp = sP4[widx];
    wx = wp.x; wy = wp.y; wz = wp.z;
    win0 = (s == t)       ? widx : win0;
    win1 = (s == t + 256) ? widx : win1;
    win2 = (s == t + 512) ? widx : win2;
    win3 = (s == t + 768) ? widx : win3;
  }
  {
    const long e0 = (long)g * MM + t;
    const float4 p0 = sP4[win0];
    fpsIdx[e0] = win0;
    ctr[e0 * 3 + 0] = p0.x; ctr[e0 * 3 + 1] = p0.y; ctr[e0 * 3 + 2] = p0.z;
    const long e1 = e0 + 256;
    const float4 p1 = sP4[win1];
    fpsIdx[e1] = win1;
    ctr[e1 * 3 + 0] = p1.x; ctr[e1 * 3 + 1] = p1.y; ctr[e1 * 3 + 2] = p1.z;
    const long e2 = e0 + 512;
    const float4 p2 = sP4[win2];
    fpsIdx[e2] = win2;
    ctr[e2 * 3 + 0] = p2.x; ctr[e2 * 3 + 1] = p2.y; ctr[e2 * 3 + 2] = p2.z;
    const long e3 = e0 + 768;
    const float4 p3 = sP4[win3];
    fpsIdx[e3] = win3;
    ctr[e3 * 3 + 0] = p3.x; ctr[e3 * 3 + 1] = p3.y; ctr[e3 * 3 + 2] = p3.z;
  }
}

// ---- Fused radius-search + rank-top-K + gather + 3-layer MLP (MFMA) + masked max ----
// r3 base, TWO changes only: (1) layer 3 split into two sequential n-tile passes
// (acc[4] + per-pass afrag reload, peak live regs ~32 -> ~20; per-column MFMA
// accumulation order unchanged => bit-identical); (2) __launch_bounds__(512,3)
// to lift occupancy 2 -> 3 blocks/CU (fit: r3 mlp is VGPR-capped at ~2 blk/CU;
// item latency ~15.6us at C=2; time = 32*L/C so C is the lever).
__global__ __launch_bounds__(512, 3) void mlp_kernel(const float* __restrict__ x,
    const float4* __restrict__ pos4, const float* __restrict__ ctr,
    const int* __restrict__ fpsIdx,
    const __bf16* __restrict__ W1t, const __bf16* __restrict__ W2t,
    const __bf16* __restrict__ W3t,
    const float* __restrict__ b1, const float* __restrict__ b2,
    const float* __restrict__ b3,
    float* __restrict__ outX, float* __restrict__ outP,
    float* __restrict__ outB, float* __restrict__ outS) {
  __shared__ __align__(16) __bf16 sMsg[64 * SM];   // 13312 B; overlays sDI (6144 B)
  __shared__ __align__(16) __bf16 sH[64 * SH];     // 17408 B
  __shared__ int sSel[KK];
  __shared__ int sCnt;
  unsigned long long* sDI = (unsigned long long*)sMsg;  // [CAP] packed (d2bits<<32 | idx)

  const int e = blockIdx.x;
  const int t = threadIdx.x;
  const int b = e >> 10;
  const int lane = t & 63, wv = t >> 6;

  if (t == 0) sCnt = 0;
  const float cx = ctr[(long)e * 3 + 0];
  const float cy = ctr[(long)e * 3 + 1];
  const float cz = ctr[(long)e * 3 + 2];
  if (t < 3) outP[(long)e * 3 + t] = ctr[(long)e * 3 + t];
  if (t == 3) { outB[e] = (float)b; outS[e] = (float)(b * NN + fpsIdx[e]); }
  const float R2 = (float)(0.2 * 0.2);
  __syncthreads();

  // Phase A: scan 4096 points (float4 loads); ballot-compact candidates to LDS.
#pragma unroll
  for (int q = 0; q < NN / 512; ++q) {
    const int p = t + q * 512;
    const float4 P = pos4[b * NN + p];
    const float dx = __fsub_rn(cx, P.x);
    const float dy = __fsub_rn(cy, P.y);
    const float dz = __fsub_rn(cz, P.z);
    const float d2 = __fadd_rn(__fadd_rn(__fmul_rn(dx, dx), __fmul_rn(dy, dy)), __fmul_rn(dz, dz));
    const bool v = d2 < R2;
    const unsigned long long mask = __ballot(v);
    int wbase = 0;
    if (lane == 0 && mask) wbase = atomicAdd(&sCnt, (int)__popcll(mask));
    wbase = __shfl(wbase, 0);
    if (v) {
      const int off = wbase + (int)__popcll(mask & ((1ull << lane) - 1ull));
      if (off < CAP)
        sDI[off] = ((unsigned long long)__float_as_uint(d2) << 32) | (unsigned)p;
    }
  }
  __syncthreads();
  int cnt = sCnt; cnt = cnt > CAP ? CAP : cnt;
  const int nsel = cnt < KK ? cnt : KK;

  // Phase B: parallel rank selection. rank(i) = #{j : key_j < key_i}; keep rank<K.
  for (int i = t; i < cnt; i += 512) {
    const unsigned long long my = sDI[i];
    int rank = 0;
#pragma unroll 8
    for (int j = 0; j < cnt; ++j) rank += (sDI[j] < my) ? 1 : 0;
    if (rank < KK) sSel[rank] = (int)(unsigned)(my & 0xffffffffu);
  }
  __syncthreads();   // sDI dead from here; sMsg may be written
  cnt = nsel;

  // Phase C: stage msg tile [64 x (64 feat | 3 dpos | zero-pad)] into LDS as bf16.
  {
    const int r = t >> 3, p = t & 7;
    float4 a = make_float4(0.f, 0.f, 0.f, 0.f), c4 = a;
    if (r < cnt) {
      const float* xr = x + (long)(b * NN + sSel[r]) * CC + p * 8;
      a  = *(const float4*)xr;
      c4 = *(const float4*)(xr + 4);
    }
    __bf16 o[8] = {(__bf16)a.x, (__bf16)a.y, (__bf16)a.z, (__bf16)a.w,
                   (__bf16)c4.x, (__bf16)c4.y, (__bf16)c4.z, (__bf16)c4.w};
    *(uint4*)&sMsg[r * SM + p * 8] = *(uint4*)o;
  }
  if (t < 64) {
    const int r = t;
    __bf16 d0 = (__bf16)0.0f, d1 = (__bf16)0.0f, d2v = (__bf16)0.0f;
    if (r < cnt) {
      const float4 P = pos4[b * NN + sSel[r]];
      d0  = (__bf16)__fsub_rn(P.x, cx);
      d1  = (__bf16)__fsub_rn(P.y, cy);
      d2v = (__bf16)__fsub_rn(P.z, cz);
    }
    sMsg[r * SM + 64] = d0;
    sMsg[r * SM + 65] = d1;
    sMsg[r * SM + 66] = d2v;
    for (int c = 67; c < SM; ++c) sMsg[r * SM + c] = (__bf16)0.0f;
  }
  __syncthreads();

  const int l15 = lane & 15, quad = lane >> 4;
  // ---- layer 1: [64 x 96] @ [96 x 128] -> sH; wave wv owns n-tile wv ----
  {
    floatx4 acc[4] = {};
    const __bf16* wrow = W1t + (wv * 16 + l15) * 96;
#pragma unroll
    for (int ks = 0; ks < 3; ++ks) {
      const bf16x8 bfrag = *(const bf16x8*)(wrow + ks * 32 + quad * 8);
#pragma unroll
      for (int mt = 0; mt < 4; ++mt) {
        const bf16x8 afrag = *(const bf16x8*)&sMsg[(mt * 16 + l15) * SM + ks * 32 + quad * 8];
        acc[mt] = __builtin_amdgcn_mfma_f32_16x16x32_bf16(afrag, bfrag, acc[mt], 0, 0, 0);
      }
    }
    const int col = wv * 16 + l15;
    const float bias = b1[col];
#pragma unroll
    for (int mt = 0; mt < 4; ++mt)
#pragma unroll
      for (int rg = 0; rg < 4; ++rg) {
        const int row = mt * 16 + quad * 4 + rg;
        float v = acc[mt][rg] + bias;
        v = v > 0.0f ? v : 0.0f;
        sH[row * SH + col] = (__bf16)v;
      }
  }
  __syncthreads();
  // ---- layer 2: [64 x 128] @ [128 x 128], IN PLACE on sH ----
  {
    floatx4 acc[4] = {};
    const __bf16* wrow = W2t + (wv * 16 + l15) * 128;
#pragma unroll
    for (int ks = 0; ks < 4; ++ks) {
      const bf16x8 bfrag = *(const bf16x8*)(wrow + ks * 32 + quad * 8);
#pragma unroll
      for (int mt = 0; mt < 4; ++mt) {
        const bf16x8 afrag = *(const bf16x8*)&sH[(mt * 16 + l15) * SH + ks * 32 + quad * 8];
        acc[mt] = __builtin_amdgcn_mfma_f32_16x16x32_bf16(afrag, bfrag, acc[mt], 0, 0, 0);
      }
    }
    __syncthreads();
    const int col = wv * 16 + l15;
    const float bias = b2[col];
#pragma unroll
    for (int mt = 0; mt < 4; ++mt)
#pragma unroll
      for (int rg = 0; rg < 4; ++rg) {
        const int row = mt * 16 + quad * 4 + rg;
        float v = acc[mt][rg] + bias;
        v = v > 0.0f ? v : 0.0f;
        sH[row * SH + col] = (__bf16)v;
      }
  }
  __syncthreads();
  // ---- layer 3: [64 x 128] @ [128 x 256]; wave owns 2 n-tiles via 2 passes ----
  // (two-pass form: acc[4] live instead of acc[2][4]; afrag reloaded per pass;
  //  per-column ks-accumulation order identical to r3 => bit-identical output)
#pragma unroll
  for (int pass = 0; pass < 2; ++pass) {
    floatx4 acc[4] = {};
    const __bf16* wrow = W3t + ((wv * 2 + pass) * 16 + l15) * 128;
#pragma unroll
    for (int ks = 0; ks < 4; ++ks) {
      const bf16x8 bfrag = *(const bf16x8*)(wrow + ks * 32 + quad * 8);
#pragma unroll
      for (int mt = 0; mt < 4; ++mt) {
        const bf16x8 afrag = *(const bf16x8*)&sH[(mt * 16 + l15) * SH + ks * 32 + quad * 8];
        acc[mt] = __builtin_amdgcn_mfma_f32_16x16x32_bf16(afrag, bfrag, acc[mt], 0, 0, 0);
      }
    }
    const int col = (wv * 2 + pass) * 16 + l15;
    const float bias = b3[col];
    float mx = 0.0f;  // centroid itself always in-radius => cnt>=1; ReLU >= 0
#pragma unroll
    for (int mt = 0; mt < 4; ++mt)
#pragma unroll
      for (int rg = 0; rg < 4; ++rg) {
        const int row = mt * 16 + quad * 4 + rg;
        float v = acc[mt][rg] + bias;
        v = v > 0.0f ? v : 0.0f;
        if (row < cnt) mx = fmaxf(mx, v);
      }
    mx = fmaxf(mx, __shfl_xor(mx, 16));
    mx = fmaxf(mx, __shfl_xor(mx, 32));
    if (quad == 0) outX[(long)e * F3 + col] = mx;
  }
}

extern "C" void kernel_launch(void* const* d_in, const int* in_sizes, int n_in,
                              void* d_out, int out_size, void* d_ws, size_t ws_size,
                              hipStream_t stream) {
  const float* x   = (const float*)d_in[0];
  const float* pos = (const float*)d_in[1];
  const float* W1  = (const float*)d_in[4];
  const float* b1  = (const float*)d_in[5];
  const float* W2  = (const float*)d_in[6];
  const float* b2  = (const float*)d_in[7];
  const float* W3  = (const float*)d_in[8];
  const float* b3  = (const float*)d_in[9];

  // Workspace layout (~778 KB)
  char* ws = (char*)d_ws;
  int*    fpsIdx = (int*)(ws);                 // 32768
  float*  ctr    = (float*)(ws + 32768);       // 98304   (ends 131072)
  __bf16* W1t    = (__bf16*)(ws + 131072);     // 24576   (ends 155648)
  __bf16* W2t    = (__bf16*)(ws + 155648);     // 32768   (ends 188416)
  __bf16* W3t    = (__bf16*)(ws + 188416);     // 65536   (ends 253952)
  float4* pos4   = (float4*)(ws + 253952);     // 524288  (ends 778240)

  float* outX = (float*)d_out;                 // [8192,256]
  float* outP = outX + (long)EE * F3;          // [8192,3]
  float* outB = outP + (long)EE * 3;           // [8192]
  float* outS = outB + EE;                     // [8192]

  // blocks: 8 FPS + 240 wprep + 128 posp (256 threads each)
  fps_prep_kernel<<<376, 256, 0, stream>>>(pos, W1, W2, W3,
                                           fpsIdx, ctr, W1t, W2t, W3t, pos4);
  mlp_kernel<<<EE, 512, 0, stream>>>(x, pos4, ctr, fpsIdx, W1t, W2t, W3t,
                                     b1, b2, b3, outX, outP, outB, outS);
}

// Round 10
// 825.359 us; speedup vs baseline: 1.4190x; 1.0527x over previous
//
#include <hip/hip_runtime.h>
#include <stdint.h>

#define BB 8
#define NN 4096
#define CC 64
#define MM 1024
#define EE (BB*MM)   // 8192 centroids
#define KK 64        // max neighbors
#define F3 256       // output channels
#define SM 104       // msg LDS stride (elements), 16B-aligned rows (208 B)
#define SH 136       // h LDS stride (elements), 16B-aligned rows (272 B)
#define CAP 768      // candidate buffer

typedef __bf16 bf16x8 __attribute__((ext_vector_type(8)));
typedef float floatx4 __attribute__((ext_vector_type(4)));

// ---- wave64 reductions via DPP (VALU latency, no LDS) ----
#define DPP_MAXSTEP(ctrl, rmask) { \
    unsigned o = (unsigned)__builtin_amdgcn_update_dpp(0, (int)v, ctrl, rmask, 0xf, false); \
    v = v > o ? v : o; }
__device__ __forceinline__ unsigned wave_umax_u32(unsigned v) {
  DPP_MAXSTEP(0x111, 0xf)
  DPP_MAXSTEP(0x112, 0xf)
  DPP_MAXSTEP(0x114, 0xf)
  DPP_MAXSTEP(0x118, 0xf)
  DPP_MAXSTEP(0x142, 0xa)
  DPP_MAXSTEP(0x143, 0xc)
  return (unsigned)__builtin_amdgcn_readlane((int)v, 63);
}
#define DPP_MINSTEP(ctrl, rmask) { \
    unsigned o = (unsigned)__builtin_amdgcn_update_dpp((int)0xffffffffu, (int)v, ctrl, rmask, 0xf, false); \
    v = v < o ? v : o; }
__device__ __forceinline__ unsigned wave_umin_u32(unsigned v) {
  DPP_MINSTEP(0x111, 0xf)
  DPP_MINSTEP(0x112, 0xf)
  DPP_MINSTEP(0x114, 0xf)
  DPP_MINSTEP(0x118, 0xf)
  DPP_MINSTEP(0x142, 0xa)
  DPP_MINSTEP(0x143, 0xc)
  return (unsigned)__builtin_amdgcn_readlane((int)v, 63);
}

// ---- FPS (blocks 0..7, 4 waves) + W transpose (8..247) + pos->float4 (248..375) ----
// Round-3-verified form (578 us measured, 3x). Structure space measured-exhausted:
// 8wv:612, 4wv:578, pk+tournament:733, ILP-paired:926, overlapped:~855-888.
// Latency-chain bound (DPP reduce + LDS exchange + barrier + dependent sP4 read);
// instruction-count surgery regresses. Do not touch.
__global__ __launch_bounds__(256) void fps_prep_kernel(
    const float* __restrict__ pos,
    const float* __restrict__ W1, const float* __restrict__ W2, const float* __restrict__ W3,
    int* __restrict__ fpsIdx, float* __restrict__ ctr,
    __bf16* __restrict__ W1t, __bf16* __restrict__ W2t, __bf16* __restrict__ W3t,
    float4* __restrict__ pos4) {
  __shared__ float4 sP4[NN];                       // 64 KB
  __shared__ unsigned long long sRed[2][4];
  const int blk = blockIdx.x;
  const int t = threadIdx.x;

  if (blk >= BB) {
    if (blk < 248) {                               // wprep: 61440 elements, 240 blocks
      const int i0 = (blk - 8) * 256 + t;
      if (i0 < 128 * 96) {
        const int n = i0 / 96, k = i0 % 96;
        W1t[i0] = (k < 67) ? (__bf16)W1[k * 128 + n] : (__bf16)0.0f;
      } else if (i0 < 128 * 96 + 128 * 128) {
        const int i = i0 - 128 * 96;
        const int n = i / 128, k = i % 128;
        W2t[i] = (__bf16)W2[k * 128 + n];
      } else {
        const int i = i0 - (128 * 96 + 128 * 128);
        const int n = i / 128, k = i % 128;
        W3t[i] = (__bf16)W3[k * 256 + n];
      }
    } else {                                       // posp: 32768 points, 128 blocks
      const int i = (blk - 248) * 256 + t;
      pos4[i] = make_float4(pos[(long)i * 3 + 0], pos[(long)i * 3 + 1],
                            pos[(long)i * 3 + 2], 0.0f);
    }
    return;
  }

  const int g = blk;
  const int lane = t & 63, wv = t >> 6;            // 4 waves
  float px[16], py[16], pz[16], mind[16];
#pragma unroll
  for (int j = 0; j < 16; ++j) {
    const int p = t + (j << 8);
    const long base = ((long)g * NN + p) * 3;
    px[j] = pos[base + 0];
    py[j] = pos[base + 1];
    pz[j] = pos[base + 2];
    mind[j] = 1e10f;
    sP4[p] = make_float4(px[j], py[j], pz[j], 0.0f);
  }
  __syncthreads();
  float wx, wy, wz;
  { const float4 w0 = sP4[0]; wx = w0.x; wy = w0.y; wz = w0.z; }
  int win0 = 0, win1 = 0, win2 = 0, win3 = 0;      // static regs, no dynamic idx
  for (int s = 1; s < MM; ++s) {
    unsigned bb = 0u, bidx = (unsigned)t;
#pragma unroll
    for (int j = 0; j < 16; ++j) {
      const float dx = __fsub_rn(px[j], wx);
      const float dy = __fsub_rn(py[j], wy);
      const float dz = __fsub_rn(pz[j], wz);
      const float d2 = __fadd_rn(__fadd_rn(__fmul_rn(dx, dx), __fmul_rn(dy, dy)), __fmul_rn(dz, dz));
      mind[j] = fminf(mind[j], d2);
      const unsigned mb = __float_as_uint(mind[j]);   // positive floats: bit order == value order
      if (mb > bb) { bb = mb; bidx = (unsigned)(t + (j << 8)); }  // strict >: smallest j on tie
    }
    const unsigned maxv = wave_umax_u32(bb);
    const unsigned cand = (bb == maxv) ? bidx : 0xffffffffu;
    const unsigned widx_w = wave_umin_u32(cand);
    if (lane == 0)
      sRed[s & 1][wv] = ((unsigned long long)maxv << 32) | (unsigned long long)(~widx_w);
    __syncthreads();
    unsigned long long m = sRed[s & 1][0];
#pragma unroll
    for (int w = 1; w < 4; ++w) {
      const unsigned long long o = sRed[s & 1][w];
      m = o > m ? o : m;
    }
    const int widx = (int)(~(unsigned)m);
    const float4 wp = sP4[widx];
    wx = wp.x; wy = wp.y; wz = wp.z;
    win0 = (s == t)       ? widx : win0;
    win1 = (s == t + 256) ? widx : win1;
    win2 = (s == t + 512) ? widx : win2;
    win3 = (s == t + 768) ? widx : win3;
  }
  {
    const long e0 = (long)g * MM + t;
    const float4 p0 = sP4[win0];
    fpsIdx[e0] = win0;
    ctr[e0 * 3 + 0] = p0.x; ctr[e0 * 3 + 1] = p0.y; ctr[e0 * 3 + 2] = p0.z;
    const long e1 = e0 + 256;
    const float4 p1 = sP4[win1];
    fpsIdx[e1] = win1;
    ctr[e1 * 3 + 0] = p1.x; ctr[e1 * 3 + 1] = p1.y; ctr[e1 * 3 + 2] = p1.z;
    const long e2 = e0 + 512;
    const float4 p2 = sP4[win2];
    fpsIdx[e2] = win2;
    ctr[e2 * 3 + 0] = p2.x; ctr[e2 * 3 + 1] = p2.y; ctr[e2 * 3 + 2] = p2.z;
    const long e3 = e0 + 768;
    const float4 p3 = sP4[win3];
    fpsIdx[e3] = win3;
    ctr[e3 * 3 + 0] = p3.x; ctr[e3 * 3 + 1] = p3.y; ctr[e3 * 3 + 2] = p3.z;
  }
}

// ---- Fused radius-search + rank-top-K + gather + 3-layer MLP (MFMA) + masked max ----
// Round-3-verified form (250 us measured). Occupancy space measured-exhausted:
// natural(2 blk/CU):250 < cap85@512thr:290 < cap85@256thr:314 — natural VGPR >85,
// spills from any cap that buys a 3rd block exceed the concurrency gain. Do not touch.
__global__ __launch_bounds__(512) void mlp_kernel(const float* __restrict__ x,
    const float4* __restrict__ pos4, const float* __restrict__ ctr,
    const int* __restrict__ fpsIdx,
    const __bf16* __restrict__ W1t, const __bf16* __restrict__ W2t,
    const __bf16* __restrict__ W3t,
    const float* __restrict__ b1, const float* __restrict__ b2,
    const float* __restrict__ b3,
    float* __restrict__ outX, float* __restrict__ outP,
    float* __restrict__ outB, float* __restrict__ outS) {
  __shared__ __align__(16) __bf16 sMsg[64 * SM];   // 13312 B; overlays sDI (6144 B)
  __shared__ __align__(16) __bf16 sH[64 * SH];     // 17408 B
  __shared__ int sSel[KK];
  __shared__ int sCnt;
  unsigned long long* sDI = (unsigned long long*)sMsg;  // [CAP] packed (d2bits<<32 | idx)

  const int e = blockIdx.x;
  const int t = threadIdx.x;
  const int b = e >> 10;
  const int lane = t & 63, wv = t >> 6;

  if (t == 0) sCnt = 0;
  const float cx = ctr[(long)e * 3 + 0];
  const float cy = ctr[(long)e * 3 + 1];
  const float cz = ctr[(long)e * 3 + 2];
  if (t < 3) outP[(long)e * 3 + t] = ctr[(long)e * 3 + t];
  if (t == 3) { outB[e] = (float)b; outS[e] = (float)(b * NN + fpsIdx[e]); }
  const float R2 = (float)(0.2 * 0.2);
  __syncthreads();

  // Phase A: scan 4096 points (float4 loads); ballot-compact candidates to LDS.
#pragma unroll
  for (int q = 0; q < NN / 512; ++q) {
    const int p = t + q * 512;
    const float4 P = pos4[b * NN + p];
    const float dx = __fsub_rn(cx, P.x);
    const float dy = __fsub_rn(cy, P.y);
    const float dz = __fsub_rn(cz, P.z);
    const float d2 = __fadd_rn(__fadd_rn(__fmul_rn(dx, dx), __fmul_rn(dy, dy)), __fmul_rn(dz, dz));
    const bool v = d2 < R2;
    const unsigned long long mask = __ballot(v);
    int wbase = 0;
    if (lane == 0 && mask) wbase = atomicAdd(&sCnt, (int)__popcll(mask));
    wbase = __shfl(wbase, 0);
    if (v) {
      const int off = wbase + (int)__popcll(mask & ((1ull << lane) - 1ull));
      if (off < CAP)
        sDI[off] = ((unsigned long long)__float_as_uint(d2) << 32) | (unsigned)p;
    }
  }
  __syncthreads();
  int cnt = sCnt; cnt = cnt > CAP ? CAP : cnt;
  const int nsel = cnt < KK ? cnt : KK;

  // Phase B: parallel rank selection. rank(i) = #{j : key_j < key_i}; keep rank<K.
  for (int i = t; i < cnt; i += 512) {
    const unsigned long long my = sDI[i];
    int rank = 0;
#pragma unroll 8
    for (int j = 0; j < cnt; ++j) rank += (sDI[j] < my) ? 1 : 0;
    if (rank < KK) sSel[rank] = (int)(unsigned)(my & 0xffffffffu);
  }
  __syncthreads();   // sDI dead from here; sMsg may be written
  cnt = nsel;

  // Phase C: stage msg tile [64 x (64 feat | 3 dpos | zero-pad)] into LDS as bf16.
  {
    const int r = t >> 3, p = t & 7;
    float4 a = make_float4(0.f, 0.f, 0.f, 0.f), c4 = a;
    if (r < cnt) {
      const float* xr = x + (long)(b * NN + sSel[r]) * CC + p * 8;
      a  = *(const float4*)xr;
      c4 = *(const float4*)(xr + 4);
    }
    __bf16 o[8] = {(__bf16)a.x, (__bf16)a.y, (__bf16)a.z, (__bf16)a.w,
                   (__bf16)c4.x, (__bf16)c4.y, (__bf16)c4.z, (__bf16)c4.w};
    *(uint4*)&sMsg[r * SM + p * 8] = *(uint4*)o;
  }
  if (t < 64) {
    const int r = t;
    __bf16 d0 = (__bf16)0.0f, d1 = (__bf16)0.0f, d2v = (__bf16)0.0f;
    if (r < cnt) {
      const float4 P = pos4[b * NN + sSel[r]];
      d0  = (__bf16)__fsub_rn(P.x, cx);
      d1  = (__bf16)__fsub_rn(P.y, cy);
      d2v = (__bf16)__fsub_rn(P.z, cz);
    }
    sMsg[r * SM + 64] = d0;
    sMsg[r * SM + 65] = d1;
    sMsg[r * SM + 66] = d2v;
    for (int c = 67; c < SM; ++c) sMsg[r * SM + c] = (__bf16)0.0f;
  }
  __syncthreads();

  const int l15 = lane & 15, quad = lane >> 4;
  // ---- layer 1: [64 x 96] @ [96 x 128] -> sH; wave wv owns n-tile wv ----
  {
    floatx4 acc[4] = {};
    const __bf16* wrow = W1t + (wv * 16 + l15) * 96;
#pragma unroll
    for (int ks = 0; ks < 3; ++ks) {
      const bf16x8 bfrag = *(const bf16x8*)(wrow + ks * 32 + quad * 8);
#pragma unroll
      for (int mt = 0; mt < 4; ++mt) {
        const bf16x8 afrag = *(const bf16x8*)&sMsg[(mt * 16 + l15) * SM + ks * 32 + quad * 8];
        acc[mt] = __builtin_amdgcn_mfma_f32_16x16x32_bf16(afrag, bfrag, acc[mt], 0, 0, 0);
      }
    }
    const int col = wv * 16 + l15;
    const float bias = b1[col];
#pragma unroll
    for (int mt = 0; mt < 4; ++mt)
#pragma unroll
      for (int rg = 0; rg < 4; ++rg) {
        const int row = mt * 16 + quad * 4 + rg;
        float v = acc[mt][rg] + bias;
        v = v > 0.0f ? v : 0.0f;
        sH[row * SH + col] = (__bf16)v;
      }
  }
  __syncthreads();
  // ---- layer 2: [64 x 128] @ [128 x 128], IN PLACE on sH ----
  {
    floatx4 acc[4] = {};
    const __bf16* wrow = W2t + (wv * 16 + l15) * 128;
#pragma unroll
    for (int ks = 0; ks < 4; ++ks) {
      const bf16x8 bfrag = *(const bf16x8*)(wrow + ks * 32 + quad * 8);
#pragma unroll
      for (int mt = 0; mt < 4; ++mt) {
        const bf16x8 afrag = *(const bf16x8*)&sH[(mt * 16 + l15) * SH + ks * 32 + quad * 8];
        acc[mt] = __builtin_amdgcn_mfma_f32_16x16x32_bf16(afrag, bfrag, acc[mt], 0, 0, 0);
      }
    }
    __syncthreads();
    const int col = wv * 16 + l15;
    const float bias = b2[col];
#pragma unroll
    for (int mt = 0; mt < 4; ++mt)
#pragma unroll
      for (int rg = 0; rg < 4; ++rg) {
        const int row = mt * 16 + quad * 4 + rg;
        float v = acc[mt][rg] + bias;
        v = v > 0.0f ? v : 0.0f;
        sH[row * SH + col] = (__bf16)v;
      }
  }
  __syncthreads();
  // ---- layer 3: [64 x 128] @ [128 x 256]; wave owns 2 n-tiles; fused masked max ----
  {
    floatx4 acc[2][4] = {};
#pragma unroll
    for (int ks = 0; ks < 4; ++ks) {
      bf16x8 afrag[4];
#pragma unroll
      for (int mt = 0; mt < 4; ++mt)
        afrag[mt] = *(const bf16x8*)&sH[(mt * 16 + l15) * SH + ks * 32 + quad * 8];
#pragma unroll
      for (int i = 0; i < 2; ++i) {
        const bf16x8 bfrag = *(const bf16x8*)(W3t + ((wv * 2 + i) * 16 + l15) * 128 + ks * 32 + quad * 8);
#pragma unroll
        for (int mt = 0; mt < 4; ++mt)
          acc[i][mt] = __builtin_amdgcn_mfma_f32_16x16x32_bf16(afrag[mt], bfrag, acc[i][mt], 0, 0, 0);
      }
    }
#pragma unroll
    for (int i = 0; i < 2; ++i) {
      const int col = (wv * 2 + i) * 16 + l15;
      const float bias = b3[col];
      float mx = 0.0f;  // centroid itself always in-radius => cnt>=1; ReLU >= 0
#pragma unroll
      for (int mt = 0; mt < 4; ++mt)
#pragma unroll
        for (int rg = 0; rg < 4; ++rg) {
          const int row = mt * 16 + quad * 4 + rg;
          float v = acc[i][mt][rg] + bias;
          v = v > 0.0f ? v : 0.0f;
          if (row < cnt) mx = fmaxf(mx, v);
        }
      mx = fmaxf(mx, __shfl_xor(mx, 16));
      mx = fmaxf(mx, __shfl_xor(mx, 32));
      if (quad == 0) outX[(long)e * F3 + col] = mx;
    }
  }
}

extern "C" void kernel_launch(void* const* d_in, const int* in_sizes, int n_in,
                              void* d_out, int out_size, void* d_ws, size_t ws_size,
                              hipStream_t stream) {
  const float* x   = (const float*)d_in[0];
  const float* pos = (const float*)d_in[1];
  const float* W1  = (const float*)d_in[4];
  const float* b1  = (const float*)d_in[5];
  const float* W2  = (const float*)d_in[6];
  const float* b2  = (const float*)d_in[7];
  const float* W3  = (const float*)d_in[8];
  const float* b3  = (const float*)d_in[9];

  // Workspace layout (~778 KB)
  char* ws = (char*)d_ws;
  int*    fpsIdx = (int*)(ws);                 // 8192*4        = 32768
  float*  ctr    = (float*)(ws + 32768);       // 8192*3*4      = 98304   (ends 131072)
  __bf16* W1t    = (__bf16*)(ws + 131072);     // 128*96*2      = 24576   (ends 155648)
  __bf16* W2t    = (__bf16*)(ws + 155648);     // 128*128*2     = 32768   (ends 188416)
  __bf16* W3t    = (__bf16*)(ws + 188416);     // 256*128*2     = 65536   (ends 253952)
  float4* pos4   = (float4*)(ws + 253952);     // 32768*16      = 524288  (ends 778240)

  float* outX = (float*)d_out;                 // [8192,256]
  float* outP = outX + (long)EE * F3;          // [8192,3]
  float* outB = outP + (long)EE * 3;           // [8192]
  float* outS = outB + EE;                     // [8192]

  // blocks: 8 FPS + 240 wprep + 128 posp (256 threads each)
  fps_prep_kernel<<<376, 256, 0, stream>>>(pos, W1, W2, W3,
                                           fpsIdx, ctr, W1t, W2t, W3t, pos4);
  mlp_kernel<<<EE, 512, 0, stream>>>(x, pos4, ctr, fpsIdx, W1t, W2t, W3t,
                                     b1, b2, b3, outX, outP, outB, outS);
}

// Round 11
// 813.766 us; speedup vs baseline: 1.4392x; 1.0142x over previous
//
#include <hip/hip_runtime.h>
#include <stdint.h>

#define BB 8
#define NN 4096
#define CC 64
#define MM 1024
#define EE (BB*MM)   // 8192 centroids
#define KK 64        // max neighbors
#define F3 256       // output channels
#define SM 104       // msg LDS stride (elements)
#define SH 136       // h LDS stride (elements)
#define CAP 768      // candidate buffer

typedef __bf16 bf16x8 __attribute__((ext_vector_type(8)));
typedef float floatx4 __attribute__((ext_vector_type(4)));

// ---- wave64 reductions via DPP (round-3-verified) ----
#define DPP_MAXSTEP(ctrl, rmask) { \
    unsigned o = (unsigned)__builtin_amdgcn_update_dpp(0, (int)v, ctrl, rmask, 0xf, false); \
    v = v > o ? v : o; }
__device__ __forceinline__ unsigned wave_umax_u32(unsigned v) {
  DPP_MAXSTEP(0x111, 0xf)
  DPP_MAXSTEP(0x112, 0xf)
  DPP_MAXSTEP(0x114, 0xf)
  DPP_MAXSTEP(0x118, 0xf)
  DPP_MAXSTEP(0x142, 0xa)
  DPP_MAXSTEP(0x143, 0xc)
  return (unsigned)__builtin_amdgcn_readlane((int)v, 63);
}
#define DPP_MINSTEP(ctrl, rmask) { \
    unsigned o = (unsigned)__builtin_amdgcn_update_dpp((int)0xffffffffu, (int)v, ctrl, rmask, 0xf, false); \
    v = v < o ? v : o; }
__device__ __forceinline__ unsigned wave_umin_u32(unsigned v) {
  DPP_MINSTEP(0x111, 0xf)
  DPP_MINSTEP(0x112, 0xf)
  DPP_MINSTEP(0x114, 0xf)
  DPP_MINSTEP(0x118, 0xf)
  DPP_MINSTEP(0x142, 0xa)
  DPP_MINSTEP(0x143, 0xc)
  return (unsigned)__builtin_amdgcn_readlane((int)v, 63);
}

// ---- MLP item body (round-3-verified numerics; r5-verified refactor) ----
__device__ __forceinline__ void mlp_item(
    int e, int b, int t,
    const float* __restrict__ x, const float4* __restrict__ pos4,
    const float* __restrict__ ctr, const int* __restrict__ fpsIdx,
    const __bf16* __restrict__ W1t, const __bf16* __restrict__ W2t,
    const __bf16* __restrict__ W3t,
    const float* __restrict__ b1, const float* __restrict__ b2,
    const float* __restrict__ b3,
    float* __restrict__ outX, float* __restrict__ outP,
    float* __restrict__ outB, float* __restrict__ outS,
    __bf16* sMsg, __bf16* sH, int* sSel, int* sCnt) {
  // caller must have set *sCnt = 0 and issued __syncthreads()
  unsigned long long* sDI = (unsigned long long*)sMsg;  // [CAP] packed (d2bits<<32 | idx)
  const int lane = t & 63, wv = t >> 6;

  const float cx = ctr[(long)e * 3 + 0];
  const float cy = ctr[(long)e * 3 + 1];
  const float cz = ctr[(long)e * 3 + 2];
  if (t < 3) outP[(long)e * 3 + t] = ctr[(long)e * 3 + t];
  if (t == 3) { outB[e] = (float)b; outS[e] = (float)(b * NN + fpsIdx[e]); }
  const float R2 = (float)(0.2 * 0.2);

  // Phase A: scan 4096 points; ballot-compact candidates to LDS.
#pragma unroll
  for (int q = 0; q < NN / 512; ++q) {
    const int p = t + q * 512;
    const float4 P = pos4[b * NN + p];
    const float dx = __fsub_rn(cx, P.x);
    const float dy = __fsub_rn(cy, P.y);
    const float dz = __fsub_rn(cz, P.z);
    const float d2 = __fadd_rn(__fadd_rn(__fmul_rn(dx, dx), __fmul_rn(dy, dy)), __fmul_rn(dz, dz));
    const bool v = d2 < R2;
    const unsigned long long mask = __ballot(v);
    int wbase = 0;
    if (lane == 0 && mask) wbase = atomicAdd(sCnt, (int)__popcll(mask));
    wbase = __shfl(wbase, 0);
    if (v) {
      const int off = wbase + (int)__popcll(mask & ((1ull << lane) - 1ull));
      if (off < CAP)
        sDI[off] = ((unsigned long long)__float_as_uint(d2) << 32) | (unsigned)p;
    }
  }
  __syncthreads();
  int cnt = *sCnt; cnt = cnt > CAP ? CAP : cnt;
  const int nsel = cnt < KK ? cnt : KK;

  // Phase B: parallel rank selection.
  for (int i = t; i < cnt; i += 512) {
    const unsigned long long my = sDI[i];
    int rank = 0;
#pragma unroll 8
    for (int j = 0; j < cnt; ++j) rank += (sDI[j] < my) ? 1 : 0;
    if (rank < KK) sSel[rank] = (int)(unsigned)(my & 0xffffffffu);
  }
  __syncthreads();
  cnt = nsel;

  // Phase C: stage msg tile into LDS as bf16.
  {
    const int r = t >> 3, p = t & 7;
    float4 a = make_float4(0.f, 0.f, 0.f, 0.f), c4 = a;
    if (r < cnt) {
      const float* xr = x + (long)(b * NN + sSel[r]) * CC + p * 8;
      a  = *(const float4*)xr;
      c4 = *(const float4*)(xr + 4);
    }
    __bf16 o[8] = {(__bf16)a.x, (__bf16)a.y, (__bf16)a.z, (__bf16)a.w,
                   (__bf16)c4.x, (__bf16)c4.y, (__bf16)c4.z, (__bf16)c4.w};
    *(uint4*)&sMsg[r * SM + p * 8] = *(uint4*)o;
  }
  if (t < 64) {
    const int r = t;
    __bf16 d0 = (__bf16)0.0f, d1 = (__bf16)0.0f, d2v = (__bf16)0.0f;
    if (r < cnt) {
      const float4 P = pos4[b * NN + sSel[r]];
      d0  = (__bf16)__fsub_rn(P.x, cx);
      d1  = (__bf16)__fsub_rn(P.y, cy);
      d2v = (__bf16)__fsub_rn(P.z, cz);
    }
    sMsg[r * SM + 64] = d0;
    sMsg[r * SM + 65] = d1;
    sMsg[r * SM + 66] = d2v;
    for (int c = 67; c < SM; ++c) sMsg[r * SM + c] = (__bf16)0.0f;
  }
  __syncthreads();

  const int l15 = lane & 15, quad = lane >> 4;
  // layer 1
  {
    floatx4 acc[4] = {};
    const __bf16* wrow = W1t + (wv * 16 + l15) * 96;
#pragma unroll
    for (int ks = 0; ks < 3; ++ks) {
      const bf16x8 bfrag = *(const bf16x8*)(wrow + ks * 32 + quad * 8);
#pragma unroll
      for (int mt = 0; mt < 4; ++mt) {
        const bf16x8 afrag = *(const bf16x8*)&sMsg[(mt * 16 + l15) * SM + ks * 32 + quad * 8];
        acc[mt] = __builtin_amdgcn_mfma_f32_16x16x32_bf16(afrag, bfrag, acc[mt], 0, 0, 0);
      }
    }
    const int col = wv * 16 + l15;
    const float bias = b1[col];
#pragma unroll
    for (int mt = 0; mt < 4; ++mt)
#pragma unroll
      for (int rg = 0; rg < 4; ++rg) {
        const int row = mt * 16 + quad * 4 + rg;
        float v = acc[mt][rg] + bias;
        v = v > 0.0f ? v : 0.0f;
        sH[row * SH + col] = (__bf16)v;
      }
  }
  __syncthreads();
  // layer 2 (in place on sH)
  {
    floatx4 acc[4] = {};
    const __bf16* wrow = W2t + (wv * 16 + l15) * 128;
#pragma unroll
    for (int ks = 0; ks < 4; ++ks) {
      const bf16x8 bfrag = *(const bf16x8*)(wrow + ks * 32 + quad * 8);
#pragma unroll
      for (int mt = 0; mt < 4; ++mt) {
        const bf16x8 afrag = *(const bf16x8*)&sH[(mt * 16 + l15) * SH + ks * 32 + quad * 8];
        acc[mt] = __builtin_amdgcn_mfma_f32_16x16x32_bf16(afrag, bfrag, acc[mt], 0, 0, 0);
      }
    }
    __syncthreads();
    const int col = wv * 16 + l15;
    const float bias = b2[col];
#pragma unroll
    for (int mt = 0; mt < 4; ++mt)
#pragma unroll
      for (int rg = 0; rg < 4; ++rg) {
        const int row = mt * 16 + quad * 4 + rg;
        float v = acc[mt][rg] + bias;
        v = v > 0.0f ? v : 0.0f;
        sH[row * SH + col] = (__bf16)v;
      }
  }
  __syncthreads();
  // layer 3 + fused masked max
  {
    floatx4 acc[2][4] = {};
#pragma unroll
    for (int ks = 0; ks < 4; ++ks) {
      bf16x8 afrag[4];
#pragma unroll
      for (int mt = 0; mt < 4; ++mt)
        afrag[mt] = *(const bf16x8*)&sH[(mt * 16 + l15) * SH + ks * 32 + quad * 8];
#pragma unroll
      for (int i = 0; i < 2; ++i) {
        const bf16x8 bfrag = *(const bf16x8*)(W3t + ((wv * 2 + i) * 16 + l15) * 128 + ks * 32 + quad * 8);
#pragma unroll
        for (int mt = 0; mt < 4; ++mt)
          acc[i][mt] = __builtin_amdgcn_mfma_f32_16x16x32_bf16(afrag[mt], bfrag, acc[i][mt], 0, 0, 0);
      }
    }
#pragma unroll
    for (int i = 0; i < 2; ++i) {
      const int col = (wv * 2 + i) * 16 + l15;
      const float bias = b3[col];
      float mx = 0.0f;
#pragma unroll
      for (int mt = 0; mt < 4; ++mt)
#pragma unroll
        for (int rg = 0; rg < 4; ++rg) {
          const int row = mt * 16 + quad * 4 + rg;
          float v = acc[i][mt][rg] + bias;
          v = v > 0.0f ? v : 0.0f;
          if (row < cnt) mx = fmaxf(mx, v);
        }
      mx = fmaxf(mx, __shfl_xor(mx, 16));
      mx = fmaxf(mx, __shfl_xor(mx, 32));
      if (quad == 0) outX[(long)e * F3 + col] = mx;
    }
  }
}

// ctl layout (dwords; each counter on its own 128B line); memset 2048 B:
#define CTL_PREP 0
#define CTL_PROG(g) (32*((g)+1))
#define CTL_QHEAD 320
#define CTL_DONE 352

// ---- Kernel A: grid 256, LDS padded to 82 KB => HW guarantees 1 block/CU
//      (2x82KB > 160KB). Discriminating experiment vs r5 (64.5KB blocks, 2/CU
//      packing): if the r4/r5 overlap slowdown was CU co-residency, FPS now
//      runs at its solo 577us while 248 exclusive-CU workers consume items as
//      produced. If it was chip-wide DVFS, A regresses to ~880 and we revert.
__global__ __launch_bounds__(512) void fps_overlap_kernel(
    const float* __restrict__ x, const float* __restrict__ pos,
    const float* __restrict__ W1, const float* __restrict__ b1,
    const float* __restrict__ W2, const float* __restrict__ b2,
    const float* __restrict__ W3, const float* __restrict__ b3,
    int* __restrict__ fpsIdx, float* __restrict__ ctr,
    __bf16* __restrict__ W1t, __bf16* __restrict__ W2t, __bf16* __restrict__ W3t,
    float4* __restrict__ pos4, unsigned* __restrict__ ctl,
    float* __restrict__ outX, float* __restrict__ outP,
    float* __restrict__ outB, float* __restrict__ outS) {
  __shared__ __align__(16) unsigned char sBuf[83968];  // 82 KB pad => exclusive CU
  __shared__ int sClaim;

  const int t = threadIdx.x;
  const int blk = blockIdx.x;

  if (blk < BB) {
    // ================= FPS producer (graph g), r3-exact 4-wave loop =================
    const int g = blk;
    float4* sP4 = (float4*)sBuf;
    unsigned long long* sRed = (unsigned long long*)(sBuf + 65536);  // [2][4]

    // prep slice: 94208 items over 8 blocks = 11776 each
    for (int k = g * 11776 + t; k < (g + 1) * 11776; k += 512) {
      if (k < 12288) {
        const int n = k / 96, kk = k % 96;
        W1t[k] = (kk < 67) ? (__bf16)W1[kk * 128 + n] : (__bf16)0.0f;
      } else if (k < 28672) {
        const int i = k - 12288, n = i / 128, kk = i % 128;
        W2t[i] = (__bf16)W2[kk * 128 + n];
      } else if (k < 61440) {
        const int i = k - 28672, n = i / 128, kk = i % 128;
        W3t[i] = (__bf16)W3[kk * 256 + n];
      } else {
        const int i = k - 61440;
        pos4[i] = make_float4(pos[(long)i * 3 + 0], pos[(long)i * 3 + 1],
                              pos[(long)i * 3 + 2], 0.0f);
      }
    }
    __threadfence();
    __syncthreads();
    if (t == 0)
      __hip_atomic_fetch_add(&ctl[CTL_PREP], 1u, __ATOMIC_RELEASE, __HIP_MEMORY_SCOPE_AGENT);

    __builtin_amdgcn_s_setprio(1);

    const int lane = t & 63, wv = t >> 6;    // working waves 0..3 (t<256)
    float px[16], py[16], pz[16], mind[16];
    if (t < 256) {
#pragma unroll
      for (int j = 0; j < 16; ++j) {
        const int p = t + (j << 8);
        const long base = ((long)g * NN + p) * 3;
        px[j] = pos[base + 0];
        py[j] = pos[base + 1];
        pz[j] = pos[base + 2];
        mind[j] = 1e10f;
        sP4[p] = make_float4(px[j], py[j], pz[j], 0.0f);
      }
    }
    __syncthreads();
    float wx = 0.f, wy = 0.f, wz = 0.f;
    if (t < 256) { const float4 w0 = sP4[0]; wx = w0.x; wy = w0.y; wz = w0.z; }
    if (t == 0) {                            // sample 0 = point 0
      const long e0 = (long)g * MM;
      ctr[e0 * 3 + 0] = wx; ctr[e0 * 3 + 1] = wy; ctr[e0 * 3 + 2] = wz;
      fpsIdx[e0] = 0;
    }
    for (int s = 1; s < MM; ++s) {
      if (t < 256) {
        // --- inner: exact r3 numerics ---
        unsigned bb = 0u, bidx = (unsigned)t;
#pragma unroll
        for (int j = 0; j < 16; ++j) {
          const float dx = __fsub_rn(px[j], wx);
          const float dy = __fsub_rn(py[j], wy);
          const float dz = __fsub_rn(pz[j], wz);
          const float d2 = __fadd_rn(__fadd_rn(__fmul_rn(dx, dx), __fmul_rn(dy, dy)), __fmul_rn(dz, dz));
          mind[j] = fminf(mind[j], d2);
          const unsigned mb = __float_as_uint(mind[j]);
          if (mb > bb) { bb = mb; bidx = (unsigned)(t + (j << 8)); }
        }
        const unsigned maxv = wave_umax_u32(bb);
        const unsigned cand = (bb == maxv) ? bidx : 0xffffffffu;
        const unsigned widx_w = wave_umin_u32(cand);
        if (lane == 0)
          sRed[(s & 1) * 4 + wv] = ((unsigned long long)maxv << 32) | (unsigned long long)(~widx_w);
      }
      __syncthreads();                       // idle waves 4..7 participate (uniform count)
      if (t < 256) {
        unsigned long long m = sRed[(s & 1) * 4 + 0];
#pragma unroll
        for (int w = 1; w < 4; ++w) {
          const unsigned long long o = sRed[(s & 1) * 4 + w];
          m = o > m ? o : m;
        }
        const int widx = (int)(~(unsigned)m);
        const float4 wp = sP4[widx];
        wx = wp.x; wy = wp.y; wz = wp.z;
        if (t == 0) {                        // stream centroid s out
          const long eo = (long)g * MM + s;
          ctr[eo * 3 + 0] = wp.x; ctr[eo * 3 + 1] = wp.y; ctr[eo * 3 + 2] = wp.z;
          fpsIdx[eo] = widx;
          if ((s & 31) == 31)                // publish every 32 (release orders prior stores)
            __hip_atomic_store(&ctl[CTL_PROG(g)], (unsigned)(s + 1),
                               __ATOMIC_RELEASE, __HIP_MEMORY_SCOPE_AGENT);
        }
      }
    }
    if (t == 0)
      __hip_atomic_fetch_add(&ctl[CTL_DONE], 1u, __ATOMIC_RELEASE, __HIP_MEMORY_SCOPE_AGENT);
    return;
  }

  // ================= persistent MLP worker (exclusive CU) =================
  {
    __bf16* sMsg = (__bf16*)sBuf;
    __bf16* sH   = (__bf16*)(sBuf + 13312);
    int* sSel    = (int*)(sBuf + 30720);
    int* sCnt    = (int*)(sBuf + 30976);

    if (t == 0) {  // weights/pos4 gate (once)
      while (__hip_atomic_load(&ctl[CTL_PREP], __ATOMIC_ACQUIRE, __HIP_MEMORY_SCOPE_AGENT) < (unsigned)BB)
        __builtin_amdgcn_s_sleep(8);
    }
    __syncthreads();

    for (;;) {
      if (t == 0) {
        unsigned c;
        const unsigned dn = __hip_atomic_load(&ctl[CTL_DONE], __ATOMIC_ACQUIRE, __HIP_MEMORY_SCOPE_AGENT);
        if (dn >= (unsigned)BB) c = EE;          // FPS done: stop claiming; drain finishes rest
        else c = __hip_atomic_fetch_add(&ctl[CTL_QHEAD], 1u, __ATOMIC_RELAXED, __HIP_MEMORY_SCOPE_AGENT);
        sClaim = (int)c;
      }
      __syncthreads();
      const int c = sClaim;
      if (c >= EE) return;
      const int g = c & 7, sidx = c >> 3;        // interleave across graphs = production order
      const int e = g * MM + sidx;
      if (t == 0) {
        while (__hip_atomic_load(&ctl[CTL_PROG(g)], __ATOMIC_ACQUIRE, __HIP_MEMORY_SCOPE_AGENT)
               <= (unsigned)sidx)
          __builtin_amdgcn_s_sleep(8);
        *sCnt = 0;
      }
      __syncthreads();
      mlp_item(e, g, t, x, pos4, ctr, fpsIdx, W1t, W2t, W3t, b1, b2, b3,
               outX, outP, outB, outS, sMsg, sH, sSel, sCnt);
      // loop-top barrier re-joins all threads before LDS reuse
    }
  }
}

// ---- Kernel B: drain remaining items (runs after A completes; no spins) ----
__global__ __launch_bounds__(512) void drain_kernel(
    const float* __restrict__ x, const float4* __restrict__ pos4,
    const float* __restrict__ ctr, const int* __restrict__ fpsIdx,
    const __bf16* __restrict__ W1t, const __bf16* __restrict__ W2t,
    const __bf16* __restrict__ W3t,
    const float* __restrict__ b1, const float* __restrict__ b2,
    const float* __restrict__ b3, unsigned* __restrict__ ctl,
    float* __restrict__ outX, float* __restrict__ outP,
    float* __restrict__ outB, float* __restrict__ outS) {
  __shared__ __align__(16) __bf16 sMsg[64 * SM];
  __shared__ __align__(16) __bf16 sH[64 * SH];
  __shared__ int sSel[KK];
  __shared__ int sCnt;
  __shared__ int sClaim;
  const int t = threadIdx.x;

  if (t == 0) {
    unsigned c = __hip_atomic_load(&ctl[CTL_QHEAD], __ATOMIC_RELAXED, __HIP_MEMORY_SCOPE_AGENT);
    if (c < (unsigned)EE)   // shortcut avoids atomic herd once queue exhausted
      c = __hip_atomic_fetch_add(&ctl[CTL_QHEAD], 1u, __ATOMIC_RELAXED, __HIP_MEMORY_SCOPE_AGENT);
    sClaim = (int)c;
    sCnt = 0;
  }
  __syncthreads();
  const int c = sClaim;
  if (c >= EE) return;
  const int g = c & 7, sidx = c >> 3;
  mlp_item(g * MM + sidx, g, t, x, pos4, ctr, fpsIdx, W1t, W2t, W3t, b1, b2, b3,
           outX, outP, outB, outS, sMsg, sH, sSel, &sCnt);
}

extern "C" void kernel_launch(void* const* d_in, const int* in_sizes, int n_in,
                              void* d_out, int out_size, void* d_ws, size_t ws_size,
                              hipStream_t stream) {
  const float* x   = (const float*)d_in[0];
  const float* pos = (const float*)d_in[1];
  const float* W1  = (const float*)d_in[4];
  const float* b1  = (const float*)d_in[5];
  const float* W2  = (const float*)d_in[6];
  const float* b2  = (const float*)d_in[7];
  const float* W3  = (const float*)d_in[8];
  const float* b3  = (const float*)d_in[9];

  // Workspace layout (~781 KB)
  char* ws = (char*)d_ws;
  int*    fpsIdx = (int*)(ws);                 // 32768              (ends 32768)
  float*  ctr    = (float*)(ws + 32768);       // 98304              (ends 131072)
  __bf16* W1t    = (__bf16*)(ws + 131072);     // 24576              (ends 155648)
  __bf16* W2t    = (__bf16*)(ws + 155648);     // 32768              (ends 188416)
  __bf16* W3t    = (__bf16*)(ws + 188416);     // 65536              (ends 253952)
  float4* pos4   = (float4*)(ws + 253952);     // 524288             (ends 778240)
  unsigned* ctl  = (unsigned*)(ws + 778240);   // 2048               (ends 780288)

  float* outX = (float*)d_out;                 // [8192,256]
  float* outP = outX + (long)EE * F3;          // [8192,3]
  float* outB = outP + (long)EE * 3;           // [8192]
  float* outS = outB + EE;                     // [8192]

  hipMemsetAsync(ctl, 0, 2048, stream);
  fps_overlap_kernel<<<256, 512, 0, stream>>>(x, pos, W1, b1, W2, b2, W3, b3,
                                              fpsIdx, ctr, W1t, W2t, W3t, pos4, ctl,
                                              outX, outP, outB, outS);
  drain_kernel<<<EE, 512, 0, stream>>>(x, pos4, ctr, fpsIdx, W1t, W2t, W3t,
                                       b1, b2, b3, ctl, outX, outP, outB, outS);
}